// Round 2
// baseline (215.394 us; speedup 1.0000x reference)
//
#include <hip/hip_runtime.h>
#include <math.h>

#define HH 4      // heads
#define DD 32     // out dim per head
#define HD 128    // H*D
#define INF 128   // node in_dim
#define EDF 64    // edge feat dim
#define NEG 0.01f
#define NB 256    // scan blocks
#define ONODES 64 // nodes per k_out block
#define CHUNK 64  // edges per k_agg chunk

// ---- DPP butterfly add within rows of 16 lanes (VALU, no LDS) -----------
template <int CTRL>
__device__ __forceinline__ float dpp_add(float v) {
    int t = __builtin_amdgcn_update_dpp(0, __float_as_int(v), CTRL, 0xF, 0xF, true);
    return v + __int_as_float(t);
}
// full 16-lane sum: quad_perm(1,0,3,2)=0xB1, quad_perm(2,3,0,1)=0x4E,
// row_half_mirror=0x141, row_mirror=0x140
__device__ __forceinline__ float red16(float v) {
    v = dpp_add<0xB1>(v);
    v = dpp_add<0x4E>(v);
    v = dpp_add<0x141>(v);
    v = dpp_add<0x140>(v);
    return v;
}

// ---- precompute collapsed weight matrices -------------------------------
__global__ void k_pre(const float* __restrict__ Wn, const float* __restrict__ We,
                      const float* __restrict__ Wa, const float* __restrict__ Wo,
                      float* __restrict__ WnA, float* __restrict__ WnB,
                      float* __restrict__ WeC, float* __restrict__ WeWo,
                      float* __restrict__ WnWo) {
    int b = blockIdx.x, tid = threadIdx.x;   // 25 blocks x 512
    if (b < 16) {
        int t = b * 512 + tid;               // t = (h*64+k)*32 + o
        int j = t >> 5, o = t & 31;
        int h = j >> 6, k = j & 63;
        float a = 0.f;
        for (int d = 0; d < DD; ++d)
            a += We[k * HD + h * DD + d] * Wo[(h * DD + d) * DD + o];
        WeWo[t] = a;
    } else if (b < 24) {
        int u = (b - 16) * 512 + tid;        // u = k*32 + o
        int k = u >> 5, o = u & 31;
        float a = 0.f;
        for (int d = 0; d < HD; ++d)
            a += Wn[k * HD + d] * Wo[d * DD + o];
        WnWo[u] = a;
    } else {
        int k = tid >> 2, h = tid & 3;
        float a = 0.f, bb = 0.f;
        for (int d = 0; d < DD; ++d) {
            float w = Wn[k * HD + h * DD + d];
            a += w * Wa[d];
            bb += w * Wa[DD + d];
        }
        WnA[k * HH + h] = a;
        WnB[k * HH + h] = bb;
        if (k < EDF) {
            float c = 0.f;
            for (int d = 0; d < DD; ++d)
                c += We[k * HD + h * DD + d] * (Wa[d] + Wa[DD + d]);
            WeC[k * HH + h] = c;
        }
    }
}

// ---- per-node attention scalars an,bn (wave per node) -------------------
__global__ void k_nodes(const float* __restrict__ X, const float* __restrict__ WnA,
                        const float* __restrict__ WnB, float* __restrict__ an,
                        float* __restrict__ bn, int N) {
    int wave = threadIdx.x >> 6, lane = threadIdx.x & 63;
    int n = blockIdx.x * 4 + wave;
    if (n >= N) return;
    float x0 = X[(size_t)n * INF + lane];
    float x1 = X[(size_t)n * INF + 64 + lane];
    float pa[HH], pb[HH];
#pragma unroll
    for (int h = 0; h < HH; ++h) {
        pa[h] = x0 * WnA[lane * HH + h] + x1 * WnA[(lane + 64) * HH + h];
        pb[h] = x0 * WnB[lane * HH + h] + x1 * WnB[(lane + 64) * HH + h];
    }
#pragma unroll
    for (int off = 32; off; off >>= 1)
#pragma unroll
        for (int h = 0; h < HH; ++h) {
            pa[h] += __shfl_xor(pa[h], off);
            pb[h] += __shfl_xor(pb[h], off);
        }
    if (lane == 0)
#pragma unroll
        for (int h = 0; h < HH; ++h) {
            an[(size_t)n * HH + h] = pa[h];
            bn[(size_t)n * HH + h] = pb[h];
        }
}

// ---- CSR build ----------------------------------------------------------
__global__ void k_init(int* __restrict__ deg, int N) {
    int i = blockIdx.x * blockDim.x + threadIdx.x;
    if (i < N) deg[i] = 0;
}
__global__ void k_hist(const int* __restrict__ dst, int* __restrict__ deg,
                       int* __restrict__ rank, int E) {
    int e = blockIdx.x * blockDim.x + threadIdx.x;
    if (e < E) rank[e] = atomicAdd(&deg[dst[e]], 1);
}
__global__ void k_scan1(const int* __restrict__ deg, int* __restrict__ partial,
                        int N, int chunk) {
    __shared__ int s[256];
    int tid = threadIdx.x;
    int i = blockIdx.x * chunk + tid;
    int v = (tid < chunk && i < N) ? deg[i] : 0;
    s[tid] = v; __syncthreads();
    for (int off = 128; off; off >>= 1) {
        if (tid < off) s[tid] += s[tid + off];
        __syncthreads();
    }
    if (tid == 0) partial[blockIdx.x] = s[0];
}
__global__ void k_scan2(const int* __restrict__ partial, int* __restrict__ pscan) {
    __shared__ int s[NB];
    int tid = threadIdx.x;
    int v = partial[tid];
    s[tid] = v; __syncthreads();
    for (int off = 1; off < NB; off <<= 1) {
        int t = (tid >= off) ? s[tid - off] : 0;
        __syncthreads();
        s[tid] += t;
        __syncthreads();
    }
    pscan[tid] = s[tid] - v;   // exclusive
}
__global__ void k_scan3(const int* __restrict__ deg, const int* __restrict__ pscan,
                        int* __restrict__ offs, int N, int chunk) {
    __shared__ int s[256];
    int tid = threadIdx.x;
    int i = blockIdx.x * chunk + tid;
    int v = (tid < chunk && i < N) ? deg[i] : 0;
    s[tid] = v; __syncthreads();
    for (int off = 1; off < 256; off <<= 1) {
        int t = (tid >= off) ? s[tid - off] : 0;
        __syncthreads();
        s[tid] += t;
        __syncthreads();
    }
    if (tid < chunk && i < N)
        offs[i] = pscan[blockIdx.x] + s[tid] - v;   // exclusive
}
__global__ void k_eids(const int* __restrict__ dst, const int* __restrict__ offs,
                       const int* __restrict__ rank, int* __restrict__ eids, int E) {
    int e = blockIdx.x * blockDim.x + threadIdx.x;
    if (e < E) eids[offs[dst[e]] + rank[e]] = e;
}

// ---- fused logits + softmax + aggregate, v3 -----------------------------
// Phase 1: logits via DPP reduce (no LDS swizzles), w -> per-wave LDS buf.
// Phase 2: lane=feature; each lane accumulates its own output feature for
// all 4 heads plus the (replicated) denominator. Zero cross-lane ops.
__global__ void k_agg(const float* __restrict__ EF, const float* __restrict__ an,
                      const float* __restrict__ bn, const float* __restrict__ WeC,
                      const int* __restrict__ src, const int* __restrict__ eids,
                      const int* __restrict__ offs, const int* __restrict__ deg,
                      float* __restrict__ Ghat, int N) {
    __shared__ float wec_s[EDF * HH];
    __shared__ float wbuf[4][CHUNK * 4];     // [wave][r*4+h]
    __shared__ int   ebuf[4][CHUNK];
    if (threadIdx.x < EDF * HH) wec_s[threadIdx.x] = WeC[threadIdx.x];
    __syncthreads();
    int wave = threadIdx.x >> 6, lane = threadIdx.x & 63;
    int g = lane >> 4, q = lane & 15;
    int n = blockIdx.x * 4 + wave;
    if (n >= N) return;
    int dn = deg[n];
    if (dn == 0) return;                     // k_out falls back to Wn path
    int st = offs[n];
    int dn1 = dn - 1;

    float wc[4][4];                          // WeC[q*4+c][h]
#pragma unroll
    for (int c = 0; c < 4; ++c)
#pragma unroll
        for (int h = 0; h < 4; ++h)
            wc[c][h] = wec_s[(q * 4 + c) * 4 + h];
    float4 bn4 = *(const float4*)(bn + (size_t)n * HH);

    float gacc[4] = {0.f, 0.f, 0.f, 0.f};    // per-lane feature, per head
    float den[4]  = {0.f, 0.f, 0.f, 0.f};    // replicated across lanes

    for (int r0 = 0; r0 < dn; r0 += CHUNK) {
        int cnt = dn - r0; if (cnt > CHUNK) cnt = CHUNK;
        int nbc = (cnt + 3) >> 2;

        // ---- phase 1: logits -> w in LDS (1-ahead pipelined loads) ----
        int rA = r0 + g;
        int eA = eids[st + (rA < dn ? rA : dn1)];
        float4 x4A = *(const float4*)(EF + (size_t)eA * EDF + q * 4);
        float4 anA = *(const float4*)(an + (size_t)src[eA] * HH);
        for (int i = 0; i < nbc; ++i) {
            int rn = r0 + (i + 1) * 4 + g;
            int eB = eids[st + (rn < dn ? rn : dn1)];
            float4 x4B = *(const float4*)(EF + (size_t)eB * EDF + q * 4);
            float4 anB = *(const float4*)(an + (size_t)src[eB] * HH);

            bool valid = (r0 + i * 4 + g) < dn;
            float ae[4];
#pragma unroll
            for (int h = 0; h < 4; ++h) {
                float p = x4A.x * wc[0][h] + x4A.y * wc[1][h]
                        + x4A.z * wc[2][h] + x4A.w * wc[3][h];
                ae[h] = red16(p);            // DPP, stays on VALU pipe
            }
            float w0, w1, w2, w3;
            {
                float l0 = anA.x + bn4.x + ae[0];
                float l1 = anA.y + bn4.y + ae[1];
                float l2 = anA.z + bn4.z + ae[2];
                float l3 = anA.w + bn4.w + ae[3];
                w0 = valid ? __expf(l0 > 0.f ? l0 : NEG * l0) : 0.f;
                w1 = valid ? __expf(l1 > 0.f ? l1 : NEG * l1) : 0.f;
                w2 = valid ? __expf(l2 > 0.f ? l2 : NEG * l2) : 0.f;
                w3 = valid ? __expf(l3 > 0.f ? l3 : NEG * l3) : 0.f;
            }
            if (q == 0) {
                *(float4*)&wbuf[wave][(i * 4 + g) * 4] = make_float4(w0, w1, w2, w3);
                ebuf[wave][i * 4 + g] = eA;
            }
            eA = eB; x4A = x4B; anA = anB;
        }
        // ---- phase 2: lane=feature accumulation (no shuffles) ---------
        // padded rows have w==0, so no validity guards needed.
        int rows = nbc * 4;
        for (int r2 = 0; r2 < rows; r2 += 4) {
            int e0 = ebuf[wave][r2 + 0];
            int e1 = ebuf[wave][r2 + 1];
            int e2 = ebuf[wave][r2 + 2];
            int e3 = ebuf[wave][r2 + 3];
            float x0 = EF[(size_t)e0 * EDF + lane];
            float x1 = EF[(size_t)e1 * EDF + lane];
            float x2 = EF[(size_t)e2 * EDF + lane];
            float x3 = EF[(size_t)e3 * EDF + lane];
            float4 wa = *(const float4*)&wbuf[wave][(r2 + 0) * 4];
            float4 wb = *(const float4*)&wbuf[wave][(r2 + 1) * 4];
            float4 wcc = *(const float4*)&wbuf[wave][(r2 + 2) * 4];
            float4 wd = *(const float4*)&wbuf[wave][(r2 + 3) * 4];
            gacc[0] += wa.x * x0 + wb.x * x1 + wcc.x * x2 + wd.x * x3;
            gacc[1] += wa.y * x0 + wb.y * x1 + wcc.y * x2 + wd.y * x3;
            gacc[2] += wa.z * x0 + wb.z * x1 + wcc.z * x2 + wd.z * x3;
            gacc[3] += wa.w * x0 + wb.w * x1 + wcc.w * x2 + wd.w * x3;
            den[0] += wa.x + wb.x + wcc.x + wd.x;
            den[1] += wa.y + wb.y + wcc.y + wd.y;
            den[2] += wa.z + wb.z + wcc.z + wd.z;
            den[3] += wa.w + wb.w + wcc.w + wd.w;
        }
    }
#pragma unroll
    for (int h = 0; h < 4; ++h)
        Ghat[(size_t)n * 256 + h * 64 + lane] = gacc[h] / den[h];
}

// ---- epilogue GEMM: out[n][o] = relu( sum_j Ghat[n][j] * WeWo[j][o] ) ---
// stage 64 Ghat rows (64KB) in LDS via coalesced float4 loads, then
// 32-lane group handles 8 nodes reading G from LDS (broadcast is free);
// weight regs amortized 8x.
__global__ void k_out(const float* __restrict__ G, const float* __restrict__ WW,
                      const float* __restrict__ X, const float* __restrict__ WnWo,
                      const int* __restrict__ deg, float* __restrict__ out, int N) {
    __shared__ float4 gs[ONODES * 64];       // 64 rows x 256 floats = 64KB
    int tid = threadIdx.x;
    int nb0 = blockIdx.x * ONODES;
    int nrem = N - nb0;
    int nloc = nrem < ONODES ? nrem : ONODES;
    const float4* Gbase = (const float4*)G + (size_t)nb0 * 64;
    for (int i = tid; i < nloc * 64; i += 256)
        gs[i] = Gbase[i];
    __syncthreads();
    int o = tid & 31, grp = tid >> 5;        // 8 groups x 8 nodes
    int t0 = grp * 8;
    float acc[8] = {0.f, 0.f, 0.f, 0.f, 0.f, 0.f, 0.f, 0.f};
    for (int j4 = 0; j4 < 64; ++j4) {
        float w0 = WW[(j4 * 4 + 0) * 32 + o];
        float w1 = WW[(j4 * 4 + 1) * 32 + o];
        float w2 = WW[(j4 * 4 + 2) * 32 + o];
        float w3 = WW[(j4 * 4 + 3) * 32 + o];
#pragma unroll
        for (int t = 0; t < 8; ++t) {
            float4 gv = gs[(t0 + t) * 64 + j4];
            acc[t] += gv.x * w0 + gv.y * w1 + gv.z * w2 + gv.w * w3;
        }
    }
#pragma unroll
    for (int t = 0; t < 8; ++t) {
        int n = nb0 + t0 + t;
        if (n >= N) break;
        float a = acc[t];
        if (deg[n] == 0) {                   // rare: z = X @ (Wn*Wo)
            a = 0.f;
            for (int k = 0; k < INF; ++k)
                a += X[(size_t)n * INF + k] * WnWo[k * DD + o];
        }
        out[(size_t)n * DD + o] = fmaxf(a, 0.f);
    }
}

extern "C" void kernel_launch(void* const* d_in, const int* in_sizes, int n_in,
                              void* d_out, int out_size, void* d_ws, size_t ws_size,
                              hipStream_t stream) {
    const float* node_feats = (const float*)d_in[0];
    const float* edge_feats = (const float*)d_in[1];
    const int*   src        = (const int*)d_in[2];
    const int*   dst        = (const int*)d_in[3];
    const float* Wn         = (const float*)d_in[4];
    const float* We         = (const float*)d_in[5];
    const float* Wa         = (const float*)d_in[6];
    const float* Wo         = (const float*)d_in[7];
    float* out = (float*)d_out;
    int N = in_sizes[0] / INF;
    int E = in_sizes[2];

    char* p = (char*)d_ws;
    auto alloc = [&](size_t bytes) {
        char* r = p;
        p += (bytes + 255) & ~(size_t)255;
        return r;
    };
    float* WnA   = (float*)alloc((size_t)INF * HH * 4);
    float* WnB   = (float*)alloc((size_t)INF * HH * 4);
    float* WeC   = (float*)alloc((size_t)EDF * HH * 4);
    float* WeWo  = (float*)alloc((size_t)EDF * HH * DD * 4);
    float* WnWo  = (float*)alloc((size_t)INF * DD * 4);
    float* an    = (float*)alloc((size_t)N * HH * 4);
    float* bn    = (float*)alloc((size_t)N * HH * 4);
    float* Ghat  = (float*)alloc((size_t)N * 256 * 4);
    int* deg     = (int*)alloc((size_t)N * 4);
    int* offs    = (int*)alloc((size_t)N * 4);
    int* rank    = (int*)alloc((size_t)E * 4);
    int* eids    = (int*)alloc((size_t)E * 4);
    int* partial = (int*)alloc((size_t)NB * 4);
    int* pscan   = (int*)alloc((size_t)NB * 4);

    int chunk = (N + NB - 1) / NB;

    hipLaunchKernelGGL(k_pre, dim3(25), dim3(512), 0, stream,
                       Wn, We, Wa, Wo, WnA, WnB, WeC, WeWo, WnWo);
    hipLaunchKernelGGL(k_nodes, dim3((N + 3) / 4), dim3(256), 0, stream,
                       node_feats, WnA, WnB, an, bn, N);
    hipLaunchKernelGGL(k_init, dim3((N + 255) / 256), dim3(256), 0, stream, deg, N);
    hipLaunchKernelGGL(k_hist, dim3((E + 255) / 256), dim3(256), 0, stream,
                       dst, deg, rank, E);
    hipLaunchKernelGGL(k_scan1, dim3(NB), dim3(256), 0, stream, deg, partial, N, chunk);
    hipLaunchKernelGGL(k_scan2, dim3(1), dim3(NB), 0, stream, partial, pscan);
    hipLaunchKernelGGL(k_scan3, dim3(NB), dim3(256), 0, stream, deg, pscan, offs, N, chunk);
    hipLaunchKernelGGL(k_eids, dim3((E + 255) / 256), dim3(256), 0, stream,
                       dst, offs, rank, eids, E);
    hipLaunchKernelGGL(k_agg, dim3((N + 3) / 4), dim3(256), 0, stream,
                       edge_feats, an, bn, WeC, src, eids, offs, deg, Ghat, N);
    hipLaunchKernelGGL(k_out, dim3((N + ONODES - 1) / ONODES), dim3(256), 0, stream,
                       Ghat, WeWo, node_feats, WnWo, deg, out, N);
}